// Round 5
// baseline (390.630 us; speedup 1.0000x reference)
//
#include <hip/hip_runtime.h>

// BackprojectDepth — R9 DIAGNOSTIC: double-launch warm-state probe.
//
// R5 (store flavor), R7 (occupancy/MLP), R8 (write topology) were ALL neutral:
// kernel pinned at ~124 us (~2.4 TB/s) while the poison fill and m13-style
// copy prove 6.3-6.4 TB/s on this chip/buffer. Remaining theory is
// environmental: the harness's 1 GiB poison fill leaves ~256 MB dirty in the
// memory-side L3; our kernel's writes share HBM with that drain
// (268 + 256 + 33 = 557 MB / 124 us = 4.5 TB/s at HBM ~= ceiling) —
// structure-invariant, matching all three neutral rounds.
//
// Probe: launch the SAME kernel twice. K2 = total_R9 - total_R8, measured
// in-bench. K2 runs debt-free with out's lines dirty-resident in L3.
//   K2 ~ 30-60 us  -> debt theory confirmed; K1 is environment-bound;
//                     single-launch 311 us was the floor -> ROOFLINE next.
//   K2 ~ 124 us    -> genuine steady-state mixed-stream limit -> also floor.
// Kernel body identical to R8 (passes verification; K2 overwrites with
// identical values).

#define BB 32
#define HH 512
#define WW 1024
#define HWN (HH * WW)        // 524288 = 2^19

typedef float vf4 __attribute__((ext_vector_type(4)));

__global__ __launch_bounds__(256) void backproject_kernel(
    const float* __restrict__ depth,   // [B, 1, H, W]
    const float* __restrict__ invK,    // [B, 4, 4]
    const int*   __restrict__ dxy,     // [B, 2]
    float*       __restrict__ out)     // [B, 4, H*W]
{
    const int gid = blockIdx.x * 256 + threadIdx.x;   // 0 .. 524287
    const int o   = gid * 4;                          // float offset inside one batch slab
    const int c   = o >> 19;                          // plane 0..3 (wave-uniform in value)
    const int n   = o & (HWN - 1);                    // pixel index of this vf4
    const float xf = (float)(n & (WW - 1));
    const float yf = (float)(n >> 10);

    const vf4 ones = {1.f, 1.f, 1.f, 1.f};

    if (c == 3) {
        // Ones plane: pure store stream, no loads. Wave-uniform branch.
        float* optr = out + o;
        #pragma unroll 4
        for (int b = 0; b < BB; ++b, optr += 4 * HWN)
            *(vf4*)optr = ones;
        return;
    }

    // c is wave-uniform — hoist to SGPR so invK row loads are scalar.
    const int cs = __builtin_amdgcn_readfirstlane(c);

    const float* dptr = depth + n;
    float*       optr = out + o;

    #pragma unroll 2
    for (int b = 0; b < BB; ++b, dptr += HWN, optr += 4 * HWN) {
        const float a0 = invK[b * 16 + cs * 4 + 0];
        const float a1 = invK[b * 16 + cs * 4 + 1];
        const float a2 = invK[b * 16 + cs * 4 + 2];
        const float dx = (float)dxy[b * 2 + 0];
        const float dy = (float)dxy[b * 2 + 1];

        const float x0 = xf + dx;
        const float cc = __builtin_fmaf(a1, yf + dy, a2);

        const vf4 d = *(const vf4*)dptr;

        vf4 r;
        r.x = d.x * __builtin_fmaf(a0, x0 + 0.f, cc);
        r.y = d.y * __builtin_fmaf(a0, x0 + 1.f, cc);
        r.z = d.z * __builtin_fmaf(a0, x0 + 2.f, cc);
        r.w = d.w * __builtin_fmaf(a0, x0 + 3.f, cc);

        *(vf4*)optr = r;
    }
}

extern "C" void kernel_launch(void* const* d_in, const int* in_sizes, int n_in,
                              void* d_out, int out_size, void* d_ws, size_t ws_size,
                              hipStream_t stream) {
    const float* depth = (const float*)d_in[0];
    const float* invK  = (const float*)d_in[1];
    const int*   dxy   = (const int*)d_in[2];
    float*       out   = (float*)d_out;

    // DIAGNOSTIC: two identical launches. K2 = dur_us(R9) - dur_us(R8)
    // measures the kernel warm (fill debt drained, out lines L3-resident).
    backproject_kernel<<<dim3(2048), 256, 0, stream>>>(depth, invK, dxy, out);
    backproject_kernel<<<dim3(2048), 256, 0, stream>>>(depth, invK, dxy, out);
}

// Round 6
// 311.894 us; speedup vs baseline: 1.2524x; 1.2524x over previous
//
#include <hip/hip_runtime.h>

// BackprojectDepth — R10: RESTORE best single-launch kernel (R4 structure).
//
// Session conclusion (R5-R9 evidence chain):
//   F (harness fixed cost) = 194 us, triple-measured (R6: 190, R8: 194, R9: 195).
//   K1 (cold kernel) = 124 us, invariant under store flavor (R5), occupancy/
//     MLP (R7), and write topology (R8).
//   K2 (warm kernel, R9 probe) = 72 us -> ~52 us of K1 is inherited drain of
//     the harness's 1 GiB poison fill (~256 MB dirty in the memory-side
//     cache), which must flush through HBM concurrently with our 268 MB
//     write-allocate. No ISA-visible lever (nt bits, topology, MLP) reaches
//     the MALL drain path — hence four neutral structural rounds.
//   Floor arithmetic: K1 >= (268 own + 33 read + ~256 debt) / 6.4 TB/s ~ 87 us;
//     measured 124 us incl. imperfect drain/allocate overlap. F + K1 ~ 312 us
//     is the environment's floor for the graded region.
//
// This file restores the best-measured variant (310.5 / 311.9 us): 2 full
// rows per block, contiguous aligned 1 KB wave-segment stores, nt on output,
// scalar invK/dxy loads. Expect ~312 us; then ROOFLINE.

#define BB 32
#define HH 512
#define WW 1024
#define HWN (HH * WW)   // 524288

typedef float vf4 __attribute__((ext_vector_type(4)));

__global__ __launch_bounds__(256) void backproject_kernel(
    const float* __restrict__ depth,   // [B, 1, H, W]
    const float* __restrict__ invK,    // [B, 4, 4]
    const int*   __restrict__ dxy,     // [B, 2]
    float*       __restrict__ out)     // [B, 4, H*W]
{
    const int tid  = threadIdx.x;
    const int b    = blockIdx.y;                 // wave-uniform
    const int row0 = blockIdx.x * 2;             // block covers rows row0, row0+1
    const int xpix = tid * 4;                    // x pixel of this thread's quad
    const int n0   = row0 * WW + xpix;           // pixel index, row 0 of pair

    // Uniform (scalar) loads
    const float k00 = invK[b * 16 + 0];
    const float k01 = invK[b * 16 + 1];
    const float k02 = invK[b * 16 + 2];
    const float k10 = invK[b * 16 + 4];
    const float k11 = invK[b * 16 + 5];
    const float k12 = invK[b * 16 + 6];
    const float k20 = invK[b * 16 + 8];
    const float k21 = invK[b * 16 + 9];
    const float k22 = invK[b * 16 + 10];
    const float dx  = (float)dxy[b * 2 + 0];
    const float dy  = (float)dxy[b * 2 + 1];

    const float x0 = (float)xpix + dx;           // same x for both rows

    // Cached (L3-served) depth loads, one per row — each contiguous per wave
    const float* dbase = depth + (size_t)b * HWN + n0;
    const vf4 da = *(const vf4*)(dbase);
    const vf4 db = *(const vf4*)(dbase + WW);

    float* outb = out + (size_t)b * 4 * HWN;
    const vf4 ones = {1.f, 1.f, 1.f, 1.f};

    #pragma unroll
    for (int h = 0; h < 2; ++h) {                // two rows
        const vf4   d = h ? db : da;
        const float y = (float)(row0 + h) + dy;
        const float c0 = k01 * y + k02;
        const float c1 = k11 * y + k12;
        const float c2 = k21 * y + k22;

        vf4 r0, r1, r2;
        r0.x = d.x * (k00 * (x0 + 0.f) + c0);
        r0.y = d.y * (k00 * (x0 + 1.f) + c0);
        r0.z = d.z * (k00 * (x0 + 2.f) + c0);
        r0.w = d.w * (k00 * (x0 + 3.f) + c0);

        r1.x = d.x * (k10 * (x0 + 0.f) + c1);
        r1.y = d.y * (k10 * (x0 + 1.f) + c1);
        r1.z = d.z * (k10 * (x0 + 2.f) + c1);
        r1.w = d.w * (k10 * (x0 + 3.f) + c1);

        r2.x = d.x * (k20 * (x0 + 0.f) + c2);
        r2.y = d.y * (k20 * (x0 + 1.f) + c2);
        r2.z = d.z * (k20 * (x0 + 2.f) + c2);
        r2.w = d.w * (k20 * (x0 + 3.f) + c2);

        const int n = n0 + h * WW;
        __builtin_nontemporal_store(r0,   (vf4*)(outb + 0 * HWN + n));
        __builtin_nontemporal_store(r1,   (vf4*)(outb + 1 * HWN + n));
        __builtin_nontemporal_store(r2,   (vf4*)(outb + 2 * HWN + n));
        __builtin_nontemporal_store(ones, (vf4*)(outb + 3 * HWN + n));
    }
}

extern "C" void kernel_launch(void* const* d_in, const int* in_sizes, int n_in,
                              void* d_out, int out_size, void* d_ws, size_t ws_size,
                              hipStream_t stream) {
    const float* depth = (const float*)d_in[0];
    const float* invK  = (const float*)d_in[1];
    const int*   dxy   = (const int*)d_in[2];
    float*       out   = (float*)d_out;

    dim3 grid(HH / 2, BB);   // 256 x 32 blocks, each does 2 rows of one batch
    backproject_kernel<<<grid, 256, 0, stream>>>(depth, invK, dxy, out);
}